// Round 2
// baseline (200.782 us; speedup 1.0000x reference)
//
#include <hip/hip_runtime.h>

// RNN: h_s = tanh(X[s,b]*W_ih + b_ih + b_hh + W_hh @ h_{s-1}); y = W_out·h_s + b_out
// S=512, B=4096, HID=30 (padded to 32 lanes).
// Layout: 32 lanes per batch element (lane = hidden unit). 2 batch elements per
// wave; all h-exchange is wave-internal through LDS (no barriers in the loop).

#define SEQ 512
#define BATCH 4096
#define HID 30

template <int CTRL>
__device__ __forceinline__ float dpp_add_step(float x) {
  // x += value moved by DPP control CTRL; invalid source lanes contribute 0.
  int moved = __builtin_amdgcn_update_dpp(0, __float_as_int(x), CTRL, 0xf, 0xf, true);
  return x + __int_as_float(moved);
}

__global__ __launch_bounds__(256, 2) void rnn_tanh_kernel(
    const float* __restrict__ X,      // [SEQ, BATCH]
    const float* __restrict__ W_ih,   // [HID, 1]
    const float* __restrict__ W_hh,   // [HID, HID]
    const float* __restrict__ b_ih,   // [HID]
    const float* __restrict__ b_hh,   // [HID]
    const float* __restrict__ W_out,  // [1, HID]
    const float* __restrict__ b_out,  // [1]
    float* __restrict__ Y)            // [SEQ, BATCH]
{
  const int tid  = threadIdx.x;
  const int lane = tid & 31;            // hidden index (30..31 are zero-padded)
  const int g    = tid >> 5;            // group within block (0..7)
  const int gb   = blockIdx.x * 8 + g;  // batch index

  __shared__ float hlds[8][32];         // per-group hidden state h_{s-1}

  // Per-lane constants. Padded lanes (30,31) keep zeros -> h stays exactly 0.
  float wih = 0.f, bsum = 0.f, wout = 0.f;
  float wrow[32];
#pragma unroll
  for (int j = 0; j < 32; ++j) wrow[j] = 0.f;
  if (lane < HID) {
    wih  = W_ih[lane];
    bsum = b_ih[lane] + b_hh[lane];
    wout = W_out[lane];
#pragma unroll
    for (int j = 0; j < HID; ++j) wrow[j] = W_hh[lane * HID + j];
  }
  const float bout = b_out[0];

  // h_0 = 0. Wave-internal write; same wave reads it first iteration -> no barrier.
  hlds[g][lane] = 0.f;

  float xcur = X[gb];  // X[0, gb]

  for (int s = 0; s < SEQ; ++s) {
    // Prefetch next step's X one iteration ahead.
    const int sn = (s + 1 < SEQ) ? s + 1 : s;
    const float xnext = X[sn * BATCH + gb];

    float acc = fmaf(xcur, wih, bsum);

    // Broadcast-read the full previous hidden vector (8 x ds_read_b128,
    // 2 distinct addresses per wave -> conflict-free broadcast).
    const float* hp = &hlds[g][0];
#pragma unroll
    for (int k = 0; k < 8; ++k) {
      const float4 hv = *reinterpret_cast<const float4*>(hp + 4 * k);
      acc = fmaf(wrow[4 * k + 0], hv.x, acc);
      acc = fmaf(wrow[4 * k + 1], hv.y, acc);
      acc = fmaf(wrow[4 * k + 2], hv.z, acc);
      acc = fmaf(wrow[4 * k + 3], hv.w, acc);
    }

    // tanh(acc) = (e^{2t}-1)/(e^{2t}+1), clamped so e^{2t} stays finite.
    const float t = fminf(fmaxf(acc, -9.f), 9.f);
    const float e = __expf(2.f * t);
    const float h = (e - 1.f) * __builtin_amdgcn_rcpf(e + 1.f);

    // Publish h_s for next step. All lanes of this wave finished their reads
    // of h_{s-1} above (single instruction stream) -> no race, no barrier.
    hlds[g][lane] = h;

    // y[s,b] = sum_i h_i * W_out_i + b_out, reduced on the VALU pipe via DPP.
    float yp = h * wout;
    yp = dpp_add_step<0x111>(yp);  // row_shr:1
    yp = dpp_add_step<0x112>(yp);  // row_shr:2
    yp = dpp_add_step<0x114>(yp);  // row_shr:4
    yp = dpp_add_step<0x118>(yp);  // row_shr:8  -> lane15/31/47/63 hold row sums
    yp = dpp_add_step<0x142>(yp);  // row_bcast15 -> lanes 31/63 hold 32-lane sums
    if (lane == 31) Y[s * BATCH + gb] = yp + bout;

    xcur = xnext;
  }
}

extern "C" void kernel_launch(void* const* d_in, const int* in_sizes, int n_in,
                              void* d_out, int out_size, void* d_ws, size_t ws_size,
                              hipStream_t stream) {
  const float* X     = (const float*)d_in[0];
  const float* W_ih  = (const float*)d_in[1];
  const float* W_hh  = (const float*)d_in[2];
  const float* b_ih  = (const float*)d_in[3];
  const float* b_hh  = (const float*)d_in[4];
  const float* W_out = (const float*)d_in[5];
  const float* b_out = (const float*)d_in[6];
  float* Y = (float*)d_out;

  // 8 batch elements per 256-thread block -> 512 blocks, 2048 waves total.
  dim3 grid(BATCH / 8), block(256);
  rnn_tanh_kernel<<<grid, block, 0, stream>>>(X, W_ih, W_hh, b_ih, b_hh,
                                              W_out, b_out, Y);
}

// Round 3
// 124.083 us; speedup vs baseline: 1.6181x; 1.6181x over previous
//
#include <hip/hip_runtime.h>

// RNN: h_s = tanh(X[s,b]*W_ih + b_ih + b_hh + W_hh @ h_{s-1}); y = W_out·h_s + b_out
// S=512, B=4096, HID=30 (padded to 32 lanes).
// Layout: 32 lanes per batch element (lane = hidden unit); 2 groups per wave;
// h-exchange wave-internal via LDS (no barriers). Depth-4 X prefetch,
// 4-way split accumulators, software-pipelined LDS h reads.

#define SEQ 512
#define BATCH 4096
#define HID 30

template <int CTRL>
__device__ __forceinline__ float dpp_add_step(float x) {
  int moved = __builtin_amdgcn_update_dpp(0, __float_as_int(x), CTRL, 0xf, 0xf, true);
  return x + __int_as_float(moved);
}

__global__ __launch_bounds__(256, 2) void rnn_tanh_kernel(
    const float* __restrict__ X,      // [SEQ, BATCH]
    const float* __restrict__ W_ih,   // [HID, 1]
    const float* __restrict__ W_hh,   // [HID, HID]
    const float* __restrict__ b_ih,   // [HID]
    const float* __restrict__ b_hh,   // [HID]
    const float* __restrict__ W_out,  // [1, HID]
    const float* __restrict__ b_out,  // [1]
    float* __restrict__ Y)            // [SEQ, BATCH]
{
  const int tid  = threadIdx.x;
  const int lane = tid & 31;            // hidden index (30..31 zero-padded)
  const int g    = tid >> 5;            // group within block (0..7)
  const int gb   = blockIdx.x * 8 + g;  // batch index

  __shared__ float hlds[8][32];

  float wih = 0.f, bsum = 0.f, wout = 0.f;
  float wrow[32];
#pragma unroll
  for (int j = 0; j < 32; ++j) wrow[j] = 0.f;
  if (lane < HID) {
    wih  = W_ih[lane];
    bsum = b_ih[lane] + b_hh[lane];
    wout = W_out[lane];
#pragma unroll
    for (int j = 0; j < HID; ++j) wrow[j] = W_hh[lane * HID + j];
  }
  const float bout = b_out[0];

  hlds[g][lane] = 0.f;
  const float* hp = &hlds[g][0];

  // Pre-read h regs for step 0 (zeros) — keeps the steady-state pattern uniform.
  float4 hv0 = *reinterpret_cast<const float4*>(hp + 0);
  float4 hv1 = *reinterpret_cast<const float4*>(hp + 4);
  float4 hv2 = *reinterpret_cast<const float4*>(hp + 8);
  float4 hv3 = *reinterpret_cast<const float4*>(hp + 12);
  float4 hv4 = *reinterpret_cast<const float4*>(hp + 16);
  float4 hv5 = *reinterpret_cast<const float4*>(hp + 20);
  float4 hv6 = *reinterpret_cast<const float4*>(hp + 24);
  float4 hv7 = *reinterpret_cast<const float4*>(hp + 28);

  // Depth-4 rotating X prefetch: 4 loads in flight (~1200 cy cover > ~900 cy HBM).
  float x0 = X[0 * BATCH + gb];
  float x1 = X[1 * BATCH + gb];
  float x2 = X[2 * BATCH + gb];
  float x3 = X[3 * BATCH + gb];

  auto STEP = [&](int s, float& xreg) {
    // acc init from this step's x, then refill the register 4 steps ahead.
    float a0 = fmaf(xreg, wih, bsum);
    const int snext = (s + 4 < SEQ) ? s + 4 : SEQ - 1;
    xreg = X[snext * BATCH + gb];

    // 4-way split accumulators over the preloaded h registers.
    float a1 = 0.f, a2 = 0.f, a3 = 0.f;
    a0 = fmaf(wrow[0],  hv0.x, a0); a1 = fmaf(wrow[1],  hv0.y, a1);
    a2 = fmaf(wrow[2],  hv0.z, a2); a3 = fmaf(wrow[3],  hv0.w, a3);
    a0 = fmaf(wrow[4],  hv1.x, a0); a1 = fmaf(wrow[5],  hv1.y, a1);
    a2 = fmaf(wrow[6],  hv1.z, a2); a3 = fmaf(wrow[7],  hv1.w, a3);
    a0 = fmaf(wrow[8],  hv2.x, a0); a1 = fmaf(wrow[9],  hv2.y, a1);
    a2 = fmaf(wrow[10], hv2.z, a2); a3 = fmaf(wrow[11], hv2.w, a3);
    a0 = fmaf(wrow[12], hv3.x, a0); a1 = fmaf(wrow[13], hv3.y, a1);
    a2 = fmaf(wrow[14], hv3.z, a2); a3 = fmaf(wrow[15], hv3.w, a3);
    a0 = fmaf(wrow[16], hv4.x, a0); a1 = fmaf(wrow[17], hv4.y, a1);
    a2 = fmaf(wrow[18], hv4.z, a2); a3 = fmaf(wrow[19], hv4.w, a3);
    a0 = fmaf(wrow[20], hv5.x, a0); a1 = fmaf(wrow[21], hv5.y, a1);
    a2 = fmaf(wrow[22], hv5.z, a2); a3 = fmaf(wrow[23], hv5.w, a3);
    a0 = fmaf(wrow[24], hv6.x, a0); a1 = fmaf(wrow[25], hv6.y, a1);
    a2 = fmaf(wrow[26], hv6.z, a2); a3 = fmaf(wrow[27], hv6.w, a3);
    a0 = fmaf(wrow[28], hv7.x, a0); a1 = fmaf(wrow[29], hv7.y, a1);
    a2 = fmaf(wrow[30], hv7.z, a2); a3 = fmaf(wrow[31], hv7.w, a3);
    const float acc = (a0 + a1) + (a2 + a3);

    // tanh(t) = 1 - 2/(e^{2t}+1), clamped.
    const float t = fminf(fmaxf(acc, -9.f), 9.f);
    const float e = __expf(2.f * t);
    const float h = fmaf(-2.f, __builtin_amdgcn_rcpf(e + 1.f), 1.f);

    // Publish h_s, then immediately issue next step's h reads so the LDS
    // round-trip overlaps the y-reduction + store + next acc init.
    hlds[g][lane] = h;
    hv0 = *reinterpret_cast<const float4*>(hp + 0);
    hv1 = *reinterpret_cast<const float4*>(hp + 4);
    hv2 = *reinterpret_cast<const float4*>(hp + 8);
    hv3 = *reinterpret_cast<const float4*>(hp + 12);
    hv4 = *reinterpret_cast<const float4*>(hp + 16);
    hv5 = *reinterpret_cast<const float4*>(hp + 20);
    hv6 = *reinterpret_cast<const float4*>(hp + 24);
    hv7 = *reinterpret_cast<const float4*>(hp + 28);

    // y = W_out·h + b_out via DPP reduction on the VALU pipe.
    float yp = h * wout;
    yp = dpp_add_step<0x111>(yp);  // row_shr:1
    yp = dpp_add_step<0x112>(yp);  // row_shr:2
    yp = dpp_add_step<0x114>(yp);  // row_shr:4
    yp = dpp_add_step<0x118>(yp);  // row_shr:8
    yp = dpp_add_step<0x142>(yp);  // row_bcast15 -> lanes 31/63 hold group sums
    if (lane == 31) Y[s * BATCH + gb] = yp + bout;
  };

  for (int s = 0; s < SEQ; s += 4) {
    STEP(s + 0, x0);
    STEP(s + 1, x1);
    STEP(s + 2, x2);
    STEP(s + 3, x3);
  }
}

extern "C" void kernel_launch(void* const* d_in, const int* in_sizes, int n_in,
                              void* d_out, int out_size, void* d_ws, size_t ws_size,
                              hipStream_t stream) {
  const float* X     = (const float*)d_in[0];
  const float* W_ih  = (const float*)d_in[1];
  const float* W_hh  = (const float*)d_in[2];
  const float* b_ih  = (const float*)d_in[3];
  const float* b_hh  = (const float*)d_in[4];
  const float* W_out = (const float*)d_in[5];
  const float* b_out = (const float*)d_in[6];
  float* Y = (float*)d_out;

  dim3 grid(BATCH / 8), block(256);
  rnn_tanh_kernel<<<grid, block, 0, stream>>>(X, W_ih, W_hh, b_ih, b_hh,
                                              W_out, b_out, Y);
}

// Round 4
// 100.543 us; speedup vs baseline: 1.9970x; 1.2341x over previous
//
#include <hip/hip_runtime.h>

// RNN: h_s = tanh(X[s,b]*W_ih + b_ih + b_hh + W_hh @ h_{s-1}); y_s = W_out·h_s + b_out
// S=512, B=4096, HID=30 (padded to 32 lanes).
// Layout: 32 lanes per batch element (lane = hidden unit); 2 groups per wave;
// h-exchange wave-internal via LDS (no barriers). Depth-4 X prefetch, 4-way
// split accumulators, software-pipelined LDS h reads.
// Lane 30 carries the OUTPUT projection: its wrow = W_out, bsum = b_out, so its
// accumulator at step s equals y_{s-1} (dot over h_{s-1}) -> no DPP reduction.
// Weights are pinned into VGPRs via empty asm (R3: compiler re-loaded them
// per-step, VGPR_Count=40).

#define SEQ 512
#define BATCH 4096
#define HID 30

__global__ __launch_bounds__(256, 2) void rnn_tanh_kernel(
    const float* __restrict__ X,      // [SEQ, BATCH]
    const float* __restrict__ W_ih,   // [HID, 1]
    const float* __restrict__ W_hh,   // [HID, HID]
    const float* __restrict__ b_ih,   // [HID]
    const float* __restrict__ b_hh,   // [HID]
    const float* __restrict__ W_out,  // [1, HID]
    const float* __restrict__ b_out,  // [1]
    float* __restrict__ Y)            // [SEQ, BATCH]
{
  const int tid  = threadIdx.x;
  const int lane = tid & 31;            // hidden index (30 = output proj, 31 = dead)
  const int g    = tid >> 5;            // group within block (0..7)
  const int gb   = blockIdx.x * 8 + g;  // batch index

  __shared__ float hlds[8][32];

  float wih = 0.f, bsum = 0.f;
  float wrow[HID];
#pragma unroll
  for (int j = 0; j < HID; ++j) wrow[j] = 0.f;
  if (lane < HID) {
    wih  = W_ih[lane];
    bsum = b_ih[lane] + b_hh[lane];
#pragma unroll
    for (int j = 0; j < HID; ++j) wrow[j] = W_hh[lane * HID + j];
  } else if (lane == HID) {             // lane 30: output projection row
    bsum = b_out[0];
#pragma unroll
    for (int j = 0; j < HID; ++j) wrow[j] = W_out[j];
  }
  // Pin weights into arch VGPRs. Opaque to LICM/remat: the compiler cannot
  // re-load them inside the step loop.
#pragma unroll
  for (int j = 0; j < HID; ++j) asm volatile("" : "+v"(wrow[j]));
  asm volatile("" : "+v"(wih));
  asm volatile("" : "+v"(bsum));

  hlds[g][lane] = 0.f;
  const float* hp = &hlds[g][0];

  // h_{-1} registers (zeros for step 0).
  float4 hv0 = *reinterpret_cast<const float4*>(hp + 0);
  float4 hv1 = *reinterpret_cast<const float4*>(hp + 4);
  float4 hv2 = *reinterpret_cast<const float4*>(hp + 8);
  float4 hv3 = *reinterpret_cast<const float4*>(hp + 12);
  float4 hv4 = *reinterpret_cast<const float4*>(hp + 16);
  float4 hv5 = *reinterpret_cast<const float4*>(hp + 20);
  float4 hv6 = *reinterpret_cast<const float4*>(hp + 24);
  float2 hv7 = *reinterpret_cast<const float2*>(hp + 28);  // h[28], h[29]

  // Depth-4 rotating X prefetch (~1200 cy cover > ~900 cy HBM latency).
  float x0 = X[0 * BATCH + gb];
  float x1 = X[1 * BATCH + gb];
  float x2 = X[2 * BATCH + gb];
  float x3 = X[3 * BATCH + gb];

  auto FMA_PASS = [&](float init) -> float {
    float a0 = init, a1 = 0.f, a2 = 0.f, a3 = 0.f;
    a0 = fmaf(wrow[0],  hv0.x, a0); a1 = fmaf(wrow[1],  hv0.y, a1);
    a2 = fmaf(wrow[2],  hv0.z, a2); a3 = fmaf(wrow[3],  hv0.w, a3);
    a0 = fmaf(wrow[4],  hv1.x, a0); a1 = fmaf(wrow[5],  hv1.y, a1);
    a2 = fmaf(wrow[6],  hv1.z, a2); a3 = fmaf(wrow[7],  hv1.w, a3);
    a0 = fmaf(wrow[8],  hv2.x, a0); a1 = fmaf(wrow[9],  hv2.y, a1);
    a2 = fmaf(wrow[10], hv2.z, a2); a3 = fmaf(wrow[11], hv2.w, a3);
    a0 = fmaf(wrow[12], hv3.x, a0); a1 = fmaf(wrow[13], hv3.y, a1);
    a2 = fmaf(wrow[14], hv3.z, a2); a3 = fmaf(wrow[15], hv3.w, a3);
    a0 = fmaf(wrow[16], hv4.x, a0); a1 = fmaf(wrow[17], hv4.y, a1);
    a2 = fmaf(wrow[18], hv4.z, a2); a3 = fmaf(wrow[19], hv4.w, a3);
    a0 = fmaf(wrow[20], hv5.x, a0); a1 = fmaf(wrow[21], hv5.y, a1);
    a2 = fmaf(wrow[22], hv5.z, a2); a3 = fmaf(wrow[23], hv5.w, a3);
    a0 = fmaf(wrow[24], hv6.x, a0); a1 = fmaf(wrow[25], hv6.y, a1);
    a2 = fmaf(wrow[26], hv6.z, a2); a3 = fmaf(wrow[27], hv6.w, a3);
    a0 = fmaf(wrow[28], hv7.x, a0); a1 = fmaf(wrow[29], hv7.y, a1);
    return (a0 + a1) + (a2 + a3);
  };

  auto STEP = [&](int s, float& xreg) {
    float acc = FMA_PASS(fmaf(xreg, wih, bsum));
    const int snext = (s + 4 < SEQ) ? s + 4 : SEQ - 1;
    xreg = X[snext * BATCH + gb];

    // Lane 30's acc is y_{s-1} (dot over h_{s-1}), incl. b_out via bsum.
    if (lane == HID && s != 0) Y[(s - 1) * BATCH + gb] = acc;

    // tanh(t) = 1 - 2/(e^{2t}+1): med3 clamp + exp2 + rcp.
    const float t = __builtin_amdgcn_fmed3f(acc, -9.f, 9.f);
    const float e = __builtin_amdgcn_exp2f(t * 2.885390081777927f);  // 2*log2(e)
    const float h = fmaf(-2.f, __builtin_amdgcn_rcpf(e + 1.f), 1.f);

    // Publish h_s, immediately issue next step's h reads (round-trip overlaps
    // the store + next acc init; wave-internal -> no barrier).
    hlds[g][lane] = h;
    hv0 = *reinterpret_cast<const float4*>(hp + 0);
    hv1 = *reinterpret_cast<const float4*>(hp + 4);
    hv2 = *reinterpret_cast<const float4*>(hp + 8);
    hv3 = *reinterpret_cast<const float4*>(hp + 12);
    hv4 = *reinterpret_cast<const float4*>(hp + 16);
    hv5 = *reinterpret_cast<const float4*>(hp + 20);
    hv6 = *reinterpret_cast<const float4*>(hp + 24);
    hv7 = *reinterpret_cast<const float2*>(hp + 28);
  };

  for (int s = 0; s < SEQ; s += 4) {
    STEP(s + 0, x0);
    STEP(s + 1, x1);
    STEP(s + 2, x2);
    STEP(s + 3, x3);
  }

  // Epilogue: hv now holds h_{SEQ-1}; lane 30's dot gives y_{SEQ-1}.
  const float ylast = FMA_PASS(bsum);
  if (lane == HID) Y[(SEQ - 1) * BATCH + gb] = ylast;
}

extern "C" void kernel_launch(void* const* d_in, const int* in_sizes, int n_in,
                              void* d_out, int out_size, void* d_ws, size_t ws_size,
                              hipStream_t stream) {
  const float* X     = (const float*)d_in[0];
  const float* W_ih  = (const float*)d_in[1];
  const float* W_hh  = (const float*)d_in[2];
  const float* b_ih  = (const float*)d_in[3];
  const float* b_hh  = (const float*)d_in[4];
  const float* W_out = (const float*)d_in[5];
  const float* b_out = (const float*)d_in[6];
  float* Y = (float*)d_out;

  dim3 grid(BATCH / 8), block(256);
  rnn_tanh_kernel<<<grid, block, 0, stream>>>(X, W_ih, W_hh, b_ih, b_hh,
                                              W_out, b_out, Y);
}